// Round 1
// 510.157 us; speedup vs baseline: 1.0043x; 1.0043x over previous
//
#include <hip/hip_runtime.h>

// GraphPool: out[i] = max(A[i], max_j A[adj_d[i - d*PER_DEG][j]]) where d = i / PER_DEG.
// Layout: 440000 rows x 128 fp32 features. Degrees 0..10, 40000 rows each, contiguous.
#define N_ATOMS 440000
#define F_DIM   128
#define PER_DEG 40000
#define MAX_DEG 10

// Native vector type so __builtin_nontemporal_store accepts it (HIP float4 is a class).
typedef float f32x4 __attribute__((ext_vector_type(4)));

// 10 adjacency pointers passed by value as a kernel argument (no device alloc needed).
struct AdjPtrs { const int* p[MAX_DEG]; };

// 256 threads/block = 8 rows/block, 32 lanes per row, one f32x4 (4 features) per lane.
// Degree is wave-uniform: 2 rows per wave, degree changes only at row multiples of 40000.
__global__ __launch_bounds__(256) void graphpool_kernel(
    const f32x4* __restrict__ A,   // atom_features viewed as f32x4, row stride 32
    AdjPtrs adj,
    f32x4* __restrict__ out)
{
    const int tid  = blockIdx.x * 256 + threadIdx.x;
    const int row  = tid >> 5;        // output row
    const int lane = tid & 31;        // f32x4 slot within the row
    if (row >= N_ATOMS) return;

    const int d     = row / PER_DEG;            // 0..10 (magic-mul, wave-uniform)
    const int local = row - d * PER_DEG;

    const size_t rbase = (size_t)row * (F_DIM / 4);
    f32x4 v = A[rbase + lane];                  // self features (normal, cache-resident)

    if (d > 0) {
        const int* idx = adj.p[d - 1] + (size_t)local * d;

        // Prefetch all indices first (contiguous ints, broadcast across the 32 lanes),
        // so the gather loads below are independent and can all be in flight at once.
        int nbrs[MAX_DEG];
        #pragma unroll
        for (int j = 0; j < MAX_DEG; ++j) {
            if (j < d) nbrs[j] = idx[j];
        }

        #pragma unroll
        for (int j = 0; j < MAX_DEG; ++j) {
            if (j < d) {
                const f32x4 nv = A[(size_t)nbrs[j] * (F_DIM / 4) + lane];
                v.x = fmaxf(v.x, nv.x);
                v.y = fmaxf(v.y, nv.y);
                v.z = fmaxf(v.z, nv.z);
                v.w = fmaxf(v.w, nv.w);
            }
        }
    }

    // Output is written once and never re-read here: bypass cache allocation (nt)
    // so the LLC keeps the 225 MB feature array resident for the gathers.
    __builtin_nontemporal_store(v, &out[rbase + lane]);
}

extern "C" void kernel_launch(void* const* d_in, const int* in_sizes, int n_in,
                              void* d_out, int out_size, void* d_ws, size_t ws_size,
                              hipStream_t stream) {
    // d_in[0] = atom_features (float32, 440000*128)
    // d_in[1] = deg_slice (int32, 11x2) -- structure is fixed by setup_inputs; not needed
    // d_in[2..11] = adj1..adj10 (int32, 40000*d each)
    const f32x4* A = (const f32x4*)d_in[0];
    AdjPtrs adj;
    for (int i = 0; i < MAX_DEG; ++i) adj.p[i] = (const int*)d_in[2 + i];
    f32x4* out = (f32x4*)d_out;

    const int total_threads = N_ATOMS * 32;      // 32 lanes per row
    const int blocks = (total_threads + 255) / 256;
    graphpool_kernel<<<blocks, 256, 0, stream>>>(A, adj, out);
}

// Round 2
// 504.868 us; speedup vs baseline: 1.0148x; 1.0105x over previous
//
#include <hip/hip_runtime.h>

// GraphPool: out[i] = max(A[i], max_j A[adj_d[i - d*PER_DEG][j]]) where d = i / PER_DEG.
// Layout: 440000 rows x 128 fp32 features. Degrees 0..10, 40000 rows each, contiguous.
#define N_ATOMS 440000
#define F_DIM   128
#define PER_DEG 40000
#define MAX_DEG 10

// LLC blocking: process the feature dim in 4 column slices of 32 floats (128 B/row).
// Per phase the gather working set is a 56 MB slice of A -> resident in the 256 MB
// Infinity Cache, so random gathers hit cache instead of HBM. Blocks are ordered
// phase-major (launch order ~ blockIdx order; locality heuristic only, not correctness).
#define PHASES          4
#define LANES_PER_ROW   8                       // 8 x f32x4 = 32 floats = 128 B slice
#define ROWS_PER_BLOCK  32                      // 256 threads / 8 lanes per row
#define BLOCKS_PER_PHASE (N_ATOMS / ROWS_PER_BLOCK)   // 13750 (exact: 40000 % 32 == 0)

// Native vector type so __builtin_nontemporal_store accepts it (HIP float4 is a class).
typedef float f32x4 __attribute__((ext_vector_type(4)));

// 10 adjacency pointers passed by value as a kernel argument (no device alloc needed).
struct AdjPtrs { const int* p[MAX_DEG]; };

__global__ __launch_bounds__(256) void graphpool_kernel(
    const f32x4* __restrict__ A,   // atom_features viewed as f32x4, row stride 32
    AdjPtrs adj,
    f32x4* __restrict__ out)
{
    const int phase = blockIdx.x / BLOCKS_PER_PHASE;          // 0..3 (compile-time magic-mul)
    const int rblk  = blockIdx.x - phase * BLOCKS_PER_PHASE;
    const int row   = rblk * ROWS_PER_BLOCK + (threadIdx.x >> 3);
    const int slot  = (phase << 3) + (threadIdx.x & 7);       // f32x4 slot 0..31
    // 40000 % 32 == 0 -> degree is uniform across the whole block.
    const int d     = row / PER_DEG;                          // 0..10
    const int local = row - d * PER_DEG;

    const size_t rbase = (size_t)row * (F_DIM / 4);
    f32x4 v = A[rbase + slot];                                // self features (one 128B line)

    if (d > 0) {
        const int* idx = adj.p[d - 1] + (size_t)local * d;

        // Prefetch all indices first (contiguous ints, broadcast across the 8 lanes),
        // so the gather loads below are independent and can all be in flight at once.
        int nbrs[MAX_DEG];
        #pragma unroll
        for (int j = 0; j < MAX_DEG; ++j) {
            if (j < d) nbrs[j] = idx[j];
        }

        #pragma unroll
        for (int j = 0; j < MAX_DEG; ++j) {
            if (j < d) {
                // One 128 B line per neighbor row per phase: line-granular, no over-fetch.
                const f32x4 nv = A[(size_t)nbrs[j] * (F_DIM / 4) + slot];
                v.x = fmaxf(v.x, nv.x);
                v.y = fmaxf(v.y, nv.y);
                v.z = fmaxf(v.z, nv.z);
                v.w = fmaxf(v.w, nv.w);
            }
        }
    }

    // nt store measured neutral at MALL level (R1); kept as harmless L1/L2 hint.
    __builtin_nontemporal_store(v, &out[rbase + slot]);
}

extern "C" void kernel_launch(void* const* d_in, const int* in_sizes, int n_in,
                              void* d_out, int out_size, void* d_ws, size_t ws_size,
                              hipStream_t stream) {
    // d_in[0] = atom_features (float32, 440000*128)
    // d_in[1] = deg_slice (int32, 11x2) -- structure is fixed by setup_inputs; not needed
    // d_in[2..11] = adj1..adj10 (int32, 40000*d each)
    const f32x4* A = (const f32x4*)d_in[0];
    AdjPtrs adj;
    for (int i = 0; i < MAX_DEG; ++i) adj.p[i] = (const int*)d_in[2 + i];
    f32x4* out = (f32x4*)d_out;

    const int blocks = BLOCKS_PER_PHASE * PHASES;   // 55000
    graphpool_kernel<<<blocks, 256, 0, stream>>>(A, adj, out);
}